// Round 6
// baseline (216.781 us; speedup 1.0000x reference)
//
#include <hip/hip_runtime.h>

// Problem dims (fixed by setup_inputs)
#define BATCH 4
#define HH 128
#define WW 128
#define CC 128
#define BIN 64
#define NPIX (BATCH * HH * WW)   // 65536

typedef short bf16x8 __attribute__((ext_vector_type(8)));
typedef float f32x4 __attribute__((ext_vector_type(4)));

// round-to-nearest-even bf16 bits of f
__device__ __forceinline__ unsigned bf_hi(float f) {
    unsigned u = __float_as_uint(f);
    return (u + 0x7fffu + ((u >> 16) & 1u)) >> 16;
}
// A-operand split: per c, k' slots [4c..4c+3] = [xh, xh, xl, xl]
__device__ __forceinline__ uint2 split_aa(float f) {
    unsigned hb = bf_hi(f);
    float lo = f - __uint_as_float(hb << 16);
    unsigned lb = bf_hi(lo);
    return make_uint2(hb | (hb << 16), lb | (lb << 16));
}

// ---------------------------------------------------------------------------
// Kernel 0: pre-split W (both convs) into bf16 [conv][d][k'=4c+slot],
// slots [wh, wl, wh, wl] (matches A's [xh,xh,xl,xl] -> full fp32 product).
// Parked in d_out (256 KB); attn fully overwrites d_out later (stream-order).
// ---------------------------------------------------------------------------
__global__ void presplit_w_kernel(const float* __restrict__ Wm,
                                  const float* __restrict__ Wr,
                                  unsigned short* __restrict__ WS) {
    const int t = blockIdx.x * 256 + threadIdx.x;   // 32768 total
    const int conv = t >> 14;
    const int d = (t >> 7) & 127;
    const int c = t & 127;
    const float* W = conv ? Wr : Wm;
    const float f = W[c * CC + d];
    const unsigned hb = bf_hi(f);
    const float lo = f - __uint_as_float(hb << 16);
    const unsigned lb = bf_hi(lo);
    const unsigned pk = hb | (lb << 16);            // [wh, wl]
    *(uint2*)(WS + ((size_t)conv * 128 + d) * 512 + c * 4) = make_uint2(pk, pk);
}

// ---------------------------------------------------------------------------
// Kernel 1: 1x1 conv via split-bf16 MFMA.
//  - A-tile (128 px x 16 c/iter) dbuf in LDS; X prefetch issued BEFORE the
//    barrier (~600+ cyc of MFMA/B-load cover vs ~300 after)
//  - B-frags straight from pre-split global W (L2-hot)
//  - launch_bounds(256,4): 4 blocks/CU resident (LDS 36.9 KB x 4 = 147 KB)
// ---------------------------------------------------------------------------
#define AROW 72

__global__ __launch_bounds__(256, 4)
void conv_mfma_kernel(const float* __restrict__ Xm, const float* __restrict__ Xr,
                      const unsigned short* __restrict__ Wsplit,
                      float* __restrict__ Ym, float* __restrict__ Yr) {
    const float* __restrict__ X = blockIdx.y ? Xr : Xm;
    const unsigned short* __restrict__ WS = Wsplit + (size_t)blockIdx.y * 128 * 512;
    float* __restrict__ Y = blockIdx.y ? Yr : Ym;

    __shared__ unsigned short AT[2][128 * AROW];   // 2 x 18 KB

    const int t  = threadIdx.x;
    const int wv = t >> 6;
    const int l  = t & 63;
    const int wm = (wv >> 1) * 64;
    const int wn = (wv & 1) * 64;
    const int lr = l & 15;
    const int lq = l >> 4;
    const int p_base = blockIdx.x * 128;
    const int px = t >> 1, ahalf = t & 1;   // 2 threads/px, 8 c each per iter

    f32x4 acc[4][4] = {};

    const float* xbase = X + (size_t)(p_base + px) * CC + ahalf * 8;
    float4 pa0 = *(const float4*)(xbase);
    float4 pa1 = *(const float4*)(xbase + 4);

    for (int k = 0; k < 8; ++k) {           // 16 c per iter
        // split prefetched regs -> AT[k&1]
        {
            unsigned short* arow = &AT[k & 1][px * AROW + ahalf * 32];
            uint2 a0 = split_aa(pa0.x), a1 = split_aa(pa0.y),
                  a2 = split_aa(pa0.z), a3 = split_aa(pa0.w);
            *(uint4*)(arow)     = make_uint4(a0.x, a0.y, a1.x, a1.y);
            *(uint4*)(arow + 8) = make_uint4(a2.x, a2.y, a3.x, a3.y);
            uint2 b0 = split_aa(pa1.x), b1 = split_aa(pa1.y),
                  b2 = split_aa(pa1.z), b3 = split_aa(pa1.w);
            *(uint4*)(arow + 16) = make_uint4(b0.x, b0.y, b1.x, b1.y);
            *(uint4*)(arow + 24) = make_uint4(b2.x, b2.y, b3.x, b3.y);
        }
        // prefetch next A chunk BEFORE the barrier: covered by barrier wait,
        // B loads and 32 MFMAs before its use at the top of iter k+1
        if (k < 7) {
            const float* xp = xbase + (k + 1) * 16;
            pa0 = *(const float4*)(xp);
            pa1 = *(const float4*)(xp + 4);
        }
        __syncthreads();
        // B-frags from global pre-split W (L2-hot)
        bf16x8 bfr[2][4];
#pragma unroll
        for (int ks = 0; ks < 2; ++ks)
#pragma unroll
            for (int ni = 0; ni < 4; ++ni)
                bfr[ks][ni] = *(const bf16x8*)(
                    WS + (size_t)(wn + ni * 16 + lr) * 512 + k * 64 + ks * 32 + lq * 8);
        // MFMA over AT[k&1]
#pragma unroll
        for (int ks = 0; ks < 2; ++ks) {
            bf16x8 af[4];
#pragma unroll
            for (int mi = 0; mi < 4; ++mi)
                af[mi] = *(const bf16x8*)&AT[k & 1][(wm + mi * 16 + lr) * AROW + ks * 32 + lq * 8];
#pragma unroll
            for (int mi = 0; mi < 4; ++mi)
#pragma unroll
                for (int ni = 0; ni < 4; ++ni)
                    acc[mi][ni] = __builtin_amdgcn_mfma_f32_16x16x32_bf16(
                        af[mi], bfr[ks][ni], acc[mi][ni], 0, 0, 0);
        }
    }

    // epilogue: C/D layout col=lane&15, row=(lane>>4)*4+reg
#pragma unroll
    for (int mi = 0; mi < 4; ++mi)
#pragma unroll
        for (int ni = 0; ni < 4; ++ni)
#pragma unroll
            for (int reg = 0; reg < 4; ++reg) {
                const int row = p_base + wm + mi * 16 + lq * 4 + reg;
                Y[(size_t)row * CC + wn + ni * 16 + lr] = acc[mi][ni][reg];
            }
}

// ---------------------------------------------------------------------------
// Kernel 2: local 5x5 attention, T=2 row-paired, 16-ch chunks, DMA dbuf.
// 128-thread blocks, TWO independent waves: wave w owns tile 2*blockIdx+w
// (16x8 px) with its own LDS region -> 4 waves/CU (vs 2 in R5).
// Halo rows padded to 21 float4 (odd stride) -> bank-conflict-free reads
// (R5's stride-20 layout cost 4 extra cyc on every ds_read_b128).
// Chunk p+1 DMA'd right after the barrier; barriers couple timing only,
// never data (each wave reads only its own buffers).
// OOB: staged addresses clamped (never used); invalid logits forced to 0
// pre-softmax and weights to 0 post-softmax == reference zero-padding.
// ---------------------------------------------------------------------------
#define T_W 16
#define T_H 8
#define HROW 21              // padded halo row stride (float4)
#define HPXP (12 * HROW)     // 252 slots per float4-group
#define CH_SLOTS 1024        // 4 groups * 252 = 1008, padded to 1024

__global__ __launch_bounds__(128, 2)
void attn_kernel(const float* __restrict__ qm, const float* __restrict__ kr,
                 const float* __restrict__ vv, float* __restrict__ out) {
    __shared__ float4 KS[2][2][CH_SLOTS];    // [wave][buf] 65.5 KB

    const int wid = threadIdx.x >> 6;        // wave id: which tile
    const int t   = threadIdx.x & 63;
    const int tile_id = blockIdx.x * 2 + wid;     // 0..511
    const int bi = tile_id >> 7;             // batch
    const int tile = tile_id & 127;
    const int ty = tile >> 3;                // 16 tile-rows (8 px tall)
    const int tx = tile & 7;                 // 8 tile-cols (16 px wide)
    const int h0 = ty * T_H, w0 = tx * T_W;
    const int c = t & 15;
    const int r = (t >> 4) * 2;              // 0,2,4,6
    const int gbase = bi * HH * WW;
    const int pix0 = gbase + (h0 + r) * WW + (w0 + c);
    const int pix1 = pix0 + WW;

    // validity masks for both pixels
    unsigned vm0 = 0, vm1 = 0;
#pragma unroll
    for (int dy = 0; dy < 5; ++dy)
#pragma unroll
        for (int dx = 0; dx < 5; ++dx) {
            const int ww = w0 + c + dx - 2;
            const bool cok = (unsigned)ww < (unsigned)WW;
            const int h_a = h0 + r + dy - 2;
            const int h_b = h_a + 1;
            if (cok && (unsigned)h_a < (unsigned)HH) vm0 |= 1u << (dy * 5 + dx);
            if (cok && (unsigned)h_b < (unsigned)HH) vm1 |= 1u << (dy * 5 + dx);
        }

    auto stage = [&](int phase, int buf) {
        const float* src = (phase < 8) ? kr : vv;
        const int ld = (phase < 8) ? CC : BIN;
        const int ch = (phase < 8) ? phase * 16 : (phase - 8) * 16;
#pragma unroll
        for (int i = 0; i < 16; ++i) {
            int s = i * 64 + t;                 // dest slot (uniform base+lane*16)
            if (s > 1007) s = 1007;             // tail: fetch a safe addr
            const int g   = s / HPXP;           // float4 group 0..3
            const int rem = s - g * HPXP;
            const int py  = rem / HROW;         // halo row 0..11
            const int pxx = rem - py * HROW;    // padded col 0..20 (20 = pad)
            int hh = h0 + py - 2;  hh = hh < 0 ? 0 : (hh > HH - 1 ? HH - 1 : hh);
            int ww = w0 + pxx - 2; ww = ww < 0 ? 0 : (ww > WW - 1 ? WW - 1 : ww);
            const float* gp = src + (size_t)(gbase + hh * WW + ww) * ld + ch + g * 4;
            __builtin_amdgcn_global_load_lds(
                (const __attribute__((address_space(1))) void*)gp,
                (__attribute__((address_space(3))) void*)&KS[wid][buf][i * 64],
                16, 0, 0);
        }
    };

    float lg0[25], lg1[25];
#pragma unroll
    for (int i = 0; i < 25; ++i) { lg0[i] = 0.0f; lg1[i] = 0.0f; }

    stage(0, 0);

    // ---- 8 logit phases (16 ch each) ----
    for (int p = 0; p < 8; ++p) {
        __syncthreads();                 // drains this wave's DMA(p)
        stage(p + 1, (p + 1) & 1);       // overlaps with compute below
        float4 q0[4], q1[4];
        {
            const float4* qp0 = (const float4*)(qm + (size_t)pix0 * CC + p * 16);
            const float4* qp1 = (const float4*)(qm + (size_t)pix1 * CC + p * 16);
#pragma unroll
            for (int g = 0; g < 4; ++g) { q0[g] = qp0[g]; q1[g] = qp1[g]; }
        }
        const float4* B = KS[wid][p & 1];
#pragma unroll
        for (int dy2 = 0; dy2 < 6; ++dy2) {
            const int hbase = (r + dy2) * HROW + c;
#pragma unroll
            for (int dx = 0; dx < 5; ++dx) {
                const int hp = hbase + dx;
#pragma unroll
                for (int g = 0; g < 4; ++g) {
                    float4 kv = B[g * HPXP + hp];
                    if (dy2 < 5)
                        lg0[dy2 * 5 + dx] += q0[g].x * kv.x + q0[g].y * kv.y +
                                             q0[g].z * kv.z + q0[g].w * kv.w;
                    if (dy2 >= 1)
                        lg1[(dy2 - 1) * 5 + dx] += q1[g].x * kv.x + q1[g].y * kv.y +
                                                   q1[g].z * kv.z + q1[g].w * kv.w;
                }
            }
        }
    }

    // ---- softmax for both pixels (overlaps with DMA of v-chunk 0) ----
    {
#pragma unroll
        for (int kk = 0; kk < 25; ++kk) {
            if (!((vm0 >> kk) & 1)) lg0[kk] = 0.0f;
            if (!((vm1 >> kk) & 1)) lg1[kk] = 0.0f;
        }
        float m0 = lg0[0], m1 = lg1[0];
#pragma unroll
        for (int kk = 1; kk < 25; ++kk) { m0 = fmaxf(m0, lg0[kk]); m1 = fmaxf(m1, lg1[kk]); }
        float s0 = 0.0f, s1 = 0.0f;
#pragma unroll
        for (int kk = 0; kk < 25; ++kk) {
            lg0[kk] = __expf(lg0[kk] - m0); s0 += lg0[kk];
            lg1[kk] = __expf(lg1[kk] - m1); s1 += lg1[kk];
        }
        const float i0 = 1.0f / s0, i1 = 1.0f / s1;
#pragma unroll
        for (int kk = 0; kk < 25; ++kk) {
            lg0[kk] = ((vm0 >> kk) & 1) ? lg0[kk] * i0 : 0.0f;
            lg1[kk] = ((vm1 >> kk) & 1) ? lg1[kk] * i1 : 0.0f;
        }
    }

    // ---- 4 value phases (16 bins each) ----
    for (int p = 8; p < 12; ++p) {
        __syncthreads();
        if (p < 11) stage(p + 1, (p + 1) & 1);
        const float4* B = KS[wid][p & 1];
        float4 va0[4], va1[4];
#pragma unroll
        for (int g = 0; g < 4; ++g) {
            va0[g] = make_float4(0.f, 0.f, 0.f, 0.f);
            va1[g] = make_float4(0.f, 0.f, 0.f, 0.f);
        }
#pragma unroll
        for (int dy2 = 0; dy2 < 6; ++dy2) {
            const int hbase = (r + dy2) * HROW + c;
#pragma unroll
            for (int dx = 0; dx < 5; ++dx) {
                const int hp = hbase + dx;
                const float w_0 = (dy2 < 5) ? lg0[dy2 * 5 + dx] : 0.0f;
                const float w_1 = (dy2 >= 1) ? lg1[(dy2 - 1) * 5 + dx] : 0.0f;
#pragma unroll
                for (int g = 0; g < 4; ++g) {
                    float4 kv = B[g * HPXP + hp];
                    if (dy2 < 5) {
                        va0[g].x += w_0 * kv.x; va0[g].y += w_0 * kv.y;
                        va0[g].z += w_0 * kv.z; va0[g].w += w_0 * kv.w;
                    }
                    if (dy2 >= 1) {
                        va1[g].x += w_1 * kv.x; va1[g].y += w_1 * kv.y;
                        va1[g].z += w_1 * kv.z; va1[g].w += w_1 * kv.w;
                    }
                }
            }
        }
        const int ch = (p - 8) * 16;
        float4* op0 = (float4*)(out + (size_t)pix0 * BIN + ch);
        float4* op1 = (float4*)(out + (size_t)pix1 * BIN + ch);
#pragma unroll
        for (int g = 0; g < 4; ++g) { op0[g] = va0[g]; op1[g] = va1[g]; }
    }
}

extern "C" void kernel_launch(void* const* d_in, const int* in_sizes, int n_in,
                              void* d_out, int out_size, void* d_ws, size_t ws_size,
                              hipStream_t stream) {
    const float* main_in   = (const float*)d_in[0];
    const float* ref_in    = (const float*)d_in[1];
    const float* ref_value = (const float*)d_in[2];
    const float* W_main    = (const float*)d_in[3];
    const float* W_ref     = (const float*)d_in[4];
    float* out = (float*)d_out;

    float* conv_main = (float*)d_ws;                       // 32 MB
    float* conv_ref  = conv_main + (size_t)NPIX * CC;      // 32 MB
    unsigned short* WS = (unsigned short*)d_out;           // parked, see above

    presplit_w_kernel<<<128, 256, 0, stream>>>(W_main, W_ref, WS);

    dim3 gconv(NPIX / 128, 2);   // 1024 blocks = 4/CU
    conv_mfma_kernel<<<gconv, 256, 0, stream>>>(main_in, ref_in, WS,
                                                conv_main, conv_ref);

    // 256 blocks x 2 independent waves = 512 tiles (16x8 px each)
    attn_kernel<<<256, 128, 0, stream>>>(conv_main, conv_ref, ref_value, out);
}

// Round 7
// 216.556 us; speedup vs baseline: 1.0010x; 1.0010x over previous
//
#include <hip/hip_runtime.h>

// Problem dims (fixed by setup_inputs)
#define BATCH 4
#define HH 128
#define WW 128
#define CC 128
#define BIN 64
#define NPIX (BATCH * HH * WW)   // 65536

typedef short bf16x8 __attribute__((ext_vector_type(8)));
typedef float f32x4 __attribute__((ext_vector_type(4)));

// round-to-nearest-even bf16 bits of f
__device__ __forceinline__ unsigned bf_hi(float f) {
    unsigned u = __float_as_uint(f);
    return (u + 0x7fffu + ((u >> 16) & 1u)) >> 16;
}
// A-operand split: per c, k' slots [4c..4c+3] = [xh, xh, xl, xl]
__device__ __forceinline__ uint2 split_aa(float f) {
    unsigned hb = bf_hi(f);
    float lo = f - __uint_as_float(hb << 16);
    unsigned lb = bf_hi(lo);
    return make_uint2(hb | (hb << 16), lb | (lb << 16));
}

// ---------------------------------------------------------------------------
// Kernel 0: pre-split W into bf16 [conv][d][k'=4c+slot], slots [wh,wl,wh,wl]
// (matches A's [xh,xh,xl,xl] -> full fp32 product). Parked in d_out (256 KB);
// attn fully overwrites d_out afterwards (stream-ordered).
// ---------------------------------------------------------------------------
__global__ void presplit_w_kernel(const float* __restrict__ Wm,
                                  const float* __restrict__ Wr,
                                  unsigned short* __restrict__ WS) {
    const int t = blockIdx.x * 256 + threadIdx.x;   // 32768 total
    const int conv = t >> 14;
    const int d = (t >> 7) & 127;
    const int c = t & 127;
    const float* W = conv ? Wr : Wm;
    const float f = W[c * CC + d];
    const unsigned hb = bf_hi(f);
    const float lo = f - __uint_as_float(hb << 16);
    const unsigned lb = bf_hi(lo);
    const unsigned pk = hb | (lb << 16);            // [wh, wl]
    *(uint2*)(WS + ((size_t)conv * 128 + d) * 512 + c * 4) = make_uint2(pk, pk);
}

// ---------------------------------------------------------------------------
// Kernel 1: 1x1 conv via split-bf16 MFMA, 64-px tiles for TLP.
// 2048 blocks (8/CU) of 256 thr; per block 64 px x 128 d; K chunked by 16 c
// (64 k'), A dbuf in LDS (18.4 KB), X reg-prefetch dist-1; B-frags straight
// from pre-split global W (L2-hot). Wave w: px-half (w&1)*32, d-half
// (w>>1)*64 -> 2x4 16x16 frags (32 acc regs).
// A row stride 72 shorts (36 dwords == 4 mod 32) -> conflict-free ds reads.
// ---------------------------------------------------------------------------
#define AROW 72

__global__ __launch_bounds__(256, 4)
void conv_mfma_kernel(const float* __restrict__ Xm, const float* __restrict__ Xr,
                      const unsigned short* __restrict__ Wsplit,
                      float* __restrict__ Ym, float* __restrict__ Yr) {
    const float* __restrict__ X = blockIdx.y ? Xr : Xm;
    const unsigned short* __restrict__ WS = Wsplit + (size_t)blockIdx.y * 128 * 512;
    float* __restrict__ Y = blockIdx.y ? Yr : Ym;

    __shared__ unsigned short AT[2][64 * AROW];   // 2 x 9.2 KB

    const int t  = threadIdx.x;
    const int wv = t >> 6;
    const int l  = t & 63;
    const int lr = l & 15;
    const int lq = l >> 4;
    const int wm = (wv & 1) * 32;    // px-half
    const int wn = (wv >> 1) * 64;   // d-half
    const int p_base = blockIdx.x * 64;
    const int px = t >> 2, q = t & 3;   // staging: 4 thr/px, 4 c each per iter

    f32x4 acc[2][4] = {};

    const float* xptr = X + (size_t)(p_base + px) * CC + q * 4;
    float4 pa = *(const float4*)xptr;

    for (int k = 0; k < 8; ++k) {       // 16 c per iter
        // split prefetched regs -> AT[k&1]
        {
            unsigned short* arow = &AT[k & 1][px * AROW + q * 16];
            uint2 a0 = split_aa(pa.x), a1 = split_aa(pa.y),
                  a2 = split_aa(pa.z), a3 = split_aa(pa.w);
            *(uint4*)(arow)     = make_uint4(a0.x, a0.y, a1.x, a1.y);
            *(uint4*)(arow + 8) = make_uint4(a2.x, a2.y, a3.x, a3.y);
        }
        if (k < 7) pa = *(const float4*)(xptr + (k + 1) * 16);
        __syncthreads();
        // B-frags from global pre-split W (L2-hot)
        bf16x8 bfr[2][4];
#pragma unroll
        for (int ks = 0; ks < 2; ++ks)
#pragma unroll
            for (int ni = 0; ni < 4; ++ni)
                bfr[ks][ni] = *(const bf16x8*)(
                    WS + (size_t)(wn + ni * 16 + lr) * 512 + k * 64 + ks * 32 + lq * 8);
#pragma unroll
        for (int ks = 0; ks < 2; ++ks) {
            bf16x8 af[2];
#pragma unroll
            for (int mi = 0; mi < 2; ++mi)
                af[mi] = *(const bf16x8*)&AT[k & 1][(wm + mi * 16 + lr) * AROW + ks * 32 + lq * 8];
#pragma unroll
            for (int mi = 0; mi < 2; ++mi)
#pragma unroll
                for (int ni = 0; ni < 4; ++ni)
                    acc[mi][ni] = __builtin_amdgcn_mfma_f32_16x16x32_bf16(
                        af[mi], bfr[ks][ni], acc[mi][ni], 0, 0, 0);
        }
    }

    // epilogue: C/D layout col=lane&15, row=(lane>>4)*4+reg
#pragma unroll
    for (int mi = 0; mi < 2; ++mi)
#pragma unroll
        for (int ni = 0; ni < 4; ++ni)
#pragma unroll
            for (int reg = 0; reg < 4; ++reg) {
                const int row = p_base + wm + mi * 16 + lq * 4 + reg;
                Y[(size_t)row * CC + wn + ni * 16 + lr] = acc[mi][ni][reg];
            }
}

// ---------------------------------------------------------------------------
// Kernel 2: local 5x5 attention, 2 threads/px (channel halves), 8x8 tiles.
// Grid 1024 x 128 thr (2 waves) -> 2048 waves; single 20.5 KB LDS buffer
// -> 6 blocks/CU = 12 waves/CU = 3 waves/SIMD (vs 1 in R6).
// Layout [half][g 0..3][py 0..11][13]: half-stride 628 fl4 (== 4 mod 8)
// puts half0 on banks 0-15, half1 on 16-31 per service octet -> all 25
// neighbor reads hit 32 distinct banks regardless of dx (fixes the constant
// 2.95M conflict cycles of R5/R6). 6 phases (4 K-ch x 32 + 2 V-bin x 32),
// staged via global_load_lds; logit halves merged with one shfl_xor(1).
// OOB: staged addrs clamped (never used); invalid logits = 0 pre-softmax
// (they DO enter the softmax sum, matching zero-padded extract_patches),
// weights = 0 post-softmax (matching zero-padded values).
// ---------------------------------------------------------------------------
#define HGRP 156          // 12 rows * 13 (padded from 12)
#define HSTR 628          // half-region stride: 4*156 + 4  (== 4 mod 8)
#define KSLOTS 1280       // 2*628 = 1256, padded for DMA tail

__global__ __launch_bounds__(128, 3)
void attn_kernel(const float* __restrict__ qm, const float* __restrict__ kr,
                 const float* __restrict__ vv, float* __restrict__ out) {
    __shared__ float4 KS[KSLOTS];   // 20.5 KB

    const int t   = threadIdx.x;
    const int wid = t >> 6;
    const int ln  = t & 63;
    const int bx  = blockIdx.x;
    const int bi  = bx >> 8;
    const int ty  = (bx >> 4) & 15;
    const int tx  = bx & 15;
    const int h0 = ty * 8, w0 = tx * 8;

    const int p    = t >> 1;      // local px 0..63
    const int half = t & 1;       // channel half
    const int r = p >> 3, c = p & 7;
    const int gbase = bi * HH * WW;
    const int pix = gbase + (h0 + r) * WW + (w0 + c);

    // 25-bit validity mask
    unsigned vm = 0;
#pragma unroll
    for (int dy = 0; dy < 5; ++dy)
#pragma unroll
        for (int dx = 0; dx < 5; ++dx) {
            const int hh = h0 + r + dy - 2, ww = w0 + c + dx - 2;
            if ((unsigned)hh < (unsigned)HH && (unsigned)ww < (unsigned)WW)
                vm |= 1u << (dy * 5 + dx);
        }

    auto stage = [&](int phase) {
        const float* src = (phase < 4) ? kr : vv;
        const int ld  = (phase < 4) ? CC : BIN;
        const int chb = (phase < 4) ? phase * 32 : (phase - 4) * 32;
#pragma unroll
        for (int i = 0; i < 10; ++i) {      // 10*128 = 1280 slots
            const int base_slot = i * 128 + wid * 64;   // wave-uniform
            int s = base_slot + ln;
            if (s > 1255) s = 1255;
            const int hr = s / HSTR;
            int rem = s - hr * HSTR;
            if (rem > 623) rem = 623;       // half-pad slots
            const int g    = hr * 4 + rem / HGRP;
            const int rem2 = rem % HGRP;
            const int py   = rem2 / 13;
            int pxx = rem2 - py * 13;
            if (pxx > 11) pxx = 11;         // row-pad slot
            int hh = h0 + py - 2;  hh = hh < 0 ? 0 : (hh > HH - 1 ? HH - 1 : hh);
            int ww = w0 + pxx - 2; ww = ww < 0 ? 0 : (ww > WW - 1 ? WW - 1 : ww);
            const float* gp = src + (size_t)(gbase + hh * WW + ww) * ld + chb + g * 4;
            __builtin_amdgcn_global_load_lds(
                (const __attribute__((address_space(1))) void*)gp,
                (__attribute__((address_space(3))) void*)&KS[base_slot],
                16, 0, 0);
        }
    };

    float lg[25];
#pragma unroll
    for (int i = 0; i < 25; ++i) lg[i] = 0.0f;

    stage(0);

    // ---- 4 logit phases: 32 ch each, this thread handles its half (16) ----
    for (int kp = 0; kp < 4; ++kp) {
        __syncthreads();                       // DMA(kp) drained
        float4 q4[4];
        {
            const float4* qp = (const float4*)(qm + (size_t)pix * CC + kp * 32 + half * 16);
#pragma unroll
            for (int gi = 0; gi < 4; ++gi) q4[gi] = qp[gi];
        }
        const float4* B = KS + half * HSTR;
#pragma unroll
        for (int dy = 0; dy < 5; ++dy)
#pragma unroll
            for (int dx = 0; dx < 5; ++dx) {
                const int hp = (r + dy) * 13 + (c + dx);
                float part = 0.0f;
#pragma unroll
                for (int gi = 0; gi < 4; ++gi) {
                    float4 kv = B[gi * HGRP + hp];
                    part += q4[gi].x * kv.x + q4[gi].y * kv.y +
                            q4[gi].z * kv.z + q4[gi].w * kv.w;
                }
                lg[dy * 5 + dx] += part;
            }
        __syncthreads();                       // all reads done
        stage(kp + 1);                         // overwrite buffer
    }

    // ---- merge halves, mask, softmax, weights ----
    {
#pragma unroll
        for (int kk = 0; kk < 25; ++kk) {
            lg[kk] += __shfl_xor(lg[kk], 1, 64);     // t <-> t^1 = other half
            if (!((vm >> kk) & 1)) lg[kk] = 0.0f;    // zero-pad logit
        }
        float mx = lg[0];
#pragma unroll
        for (int kk = 1; kk < 25; ++kk) mx = fmaxf(mx, lg[kk]);
        float sum = 0.0f;
#pragma unroll
        for (int kk = 0; kk < 25; ++kk) {
            lg[kk] = __expf(lg[kk] - mx);
            sum += lg[kk];
        }
        const float inv = 1.0f / sum;
#pragma unroll
        for (int kk = 0; kk < 25; ++kk)
            lg[kk] = ((vm >> kk) & 1) ? lg[kk] * inv : 0.0f;
    }

    // ---- 2 value phases: 32 bins each, this thread owns its 16 ----
    for (int vp = 0; vp < 2; ++vp) {
        __syncthreads();                       // DMA(4+vp) drained
        const float4* B = KS + half * HSTR;
        float4 va[4];
#pragma unroll
        for (int gi = 0; gi < 4; ++gi) va[gi] = make_float4(0.f, 0.f, 0.f, 0.f);
#pragma unroll
        for (int dy = 0; dy < 5; ++dy)
#pragma unroll
            for (int dx = 0; dx < 5; ++dx) {
                const float wgt = lg[dy * 5 + dx];
                const int hp = (r + dy) * 13 + (c + dx);
#pragma unroll
                for (int gi = 0; gi < 4; ++gi) {
                    float4 v = B[gi * HGRP + hp];
                    va[gi].x += wgt * v.x; va[gi].y += wgt * v.y;
                    va[gi].z += wgt * v.z; va[gi].w += wgt * v.w;
                }
            }
        float4* op = (float4*)(out + (size_t)pix * BIN + vp * 32 + half * 16);
#pragma unroll
        for (int gi = 0; gi < 4; ++gi) op[gi] = va[gi];
        if (vp == 0) {
            __syncthreads();                   // all reads done
            stage(5);
        }
    }
}

extern "C" void kernel_launch(void* const* d_in, const int* in_sizes, int n_in,
                              void* d_out, int out_size, void* d_ws, size_t ws_size,
                              hipStream_t stream) {
    const float* main_in   = (const float*)d_in[0];
    const float* ref_in    = (const float*)d_in[1];
    const float* ref_value = (const float*)d_in[2];
    const float* W_main    = (const float*)d_in[3];
    const float* W_ref     = (const float*)d_in[4];
    float* out = (float*)d_out;

    float* conv_main = (float*)d_ws;                       // 32 MB
    float* conv_ref  = conv_main + (size_t)NPIX * CC;      // 32 MB
    unsigned short* WS = (unsigned short*)d_out;           // parked, see above

    presplit_w_kernel<<<128, 256, 0, stream>>>(W_main, W_ref, WS);

    dim3 gconv(NPIX / 64, 2);    // 2048 blocks = 8/CU
    conv_mfma_kernel<<<gconv, 256, 0, stream>>>(main_in, ref_in, WS,
                                                conv_main, conv_ref);

    // 1024 blocks (4 bi x 16 ty x 16 tx), 128 thr = 64 px x 2 ch-halves
    attn_kernel<<<1024, 128, 0, stream>>>(conv_main, conv_ref, ref_value, out);
}